// Round 11
// baseline (346.378 us; speedup 1.0000x reference)
//
#include <hip/hip_runtime.h>

// ---------------------------------------------------------------------------
// OctreeResBlock on MI355X (gfx950), round 10:
//  - octree_sc: interleaved block order (1 octree per 4 sc) -> real overlap
//    (r10: sc dispatched after octree, only 3us overlap).
//  - Gram-trick BN3: ss3 computed BEFORE the c3 GEMM from G2 = c2^T c2
//    (mean via linearity, E[c3^2] via quadratic form). Scale folded into
//    w1bS; shortcut added via diag-MFMA (scp @ diag(ssc)). Fused final kernel
//    = c3 GEMM + both BNs + add + relu + transposed fp32 store.
//    c3p buffer and final_out kernel eliminated (-246 MB round trip).
// ---------------------------------------------------------------------------

typedef __bf16 bf16x8 __attribute__((ext_vector_type(8)));
typedef float f32x4 __attribute__((ext_vector_type(4)));
typedef unsigned short u16x8 __attribute__((ext_vector_type(8)));
typedef unsigned short u16x4 __attribute__((ext_vector_type(4)));

__device__ __forceinline__ unsigned short f2bfu(float f) {
  union { float f; unsigned u; } v; v.f = f;
  unsigned r = v.u + 0x7fffu + ((v.u >> 16) & 1u);   // round-to-nearest-even
  return (unsigned short)(r >> 16);
}
__device__ __forceinline__ float bfu2f(unsigned short s) {
  union { unsigned u; float f; } v; v.u = ((unsigned)s) << 16;
  return v.f;
}

__device__ __forceinline__ void gload_lds16(const unsigned short* g, unsigned short* l) {
  __builtin_amdgcn_global_load_lds(
      (const __attribute__((address_space(1))) unsigned int*)(unsigned long long)g,
      (__attribute__((address_space(3))) unsigned int*)(unsigned int)(unsigned long long)l,
      16, 0, 0);
}

__device__ __forceinline__ int xcd_swz(int bid, int nwg) {
  int q = nwg >> 3, r = nwg & 7;
  int xcd = bid & 7, idx = bid >> 3;
  int base = xcd < r ? xcd * (q + 1) : r * (q + 1) + (xcd - r) * q;
  return base + idx;
}

// --- fused: weights fp32->bf16 (+W3 transpose) | x transpose to h -----------
__global__ __launch_bounds__(256) void prep_transpose(
    const float* __restrict__ x, unsigned short* __restrict__ h,
    const float* __restrict__ W1a, const float* __restrict__ W3,
    const float* __restrict__ W1b, const float* __restrict__ Wc,
    unsigned short* __restrict__ w1a, unsigned short* __restrict__ w3t,
    unsigned short* __restrict__ w1b, unsigned short* __restrict__ wc,
    int M, int MT) {
  __shared__ float tile[64][65];
  int t = threadIdx.x;
  if (blockIdx.x < 432) {
    int i = blockIdx.x * 256 + t;
    for (; i < 442368; i += 432 * 256) {
      if (i < 32768)  w1a[i] = f2bfu(W1a[i]);
      if (i < 65536)  w1b[i] = f2bfu(W1b[i]);
      if (i < 131072) wc[i]  = f2bfu(Wc[i]);
      int k = i >> 14, rr = i & 16383;
      int d = rr >> 7, c = rr & 127;
      w3t[i] = f2bfu(W3[(k << 14) + (c << 7) + d]);
    }
    return;
  }
  int bid = blockIdx.x - 432;
  int n0 = (bid % MT) * 64, c0 = (bid / MT) * 64;
  int nl = t & 63;
#pragma unroll
  for (int i = 0; i < 16; ++i) {
    int cl = i * 4 + (t >> 6);
    int n = n0 + nl;
    tile[cl][nl] = (n < M) ? x[(size_t)(c0 + cl) * M + n] : 0.f;
  }
  __syncthreads();
  int cl = t & 63;
#pragma unroll
  for (int i = 0; i < 16; ++i) {
    int nl2 = i * 4 + (t >> 6);
    int n = n0 + nl2;
    h[(size_t)n * 256 + c0 + cl] = f2bfu(tile[cl][nl2]);
  }
}

// --- dense GEMM (used for c1): C = A @ W^T, r8 structure --------------------
__global__ __launch_bounds__(512, 4) void gemm128(
    const unsigned short* __restrict__ A, const unsigned short* __restrict__ W,
    unsigned short* __restrict__ C, float* __restrict__ partials,
    int M, int Kd, int Nc, int ncol) {
  __shared__ unsigned short sA[2][128 * 64];
  __shared__ unsigned short sB[2][128 * 64];
  __shared__ float sStat[8][2][128];
  int t = threadIdx.x, wave = t >> 6, lane = t & 63;
  int flat = xcd_swz(blockIdx.x, gridDim.x);
  int n0 = (flat % ncol) * 128;
  int rowt = flat / ncol;
  int m0 = rowt * 128;
  int wr = wave >> 1, wcc = wave & 1;
  int l4 = lane >> 4, lc = lane & 15, lc7 = lc & 7;
  int lrow = lane >> 3, lch = lane & 7;
  f32x4 acc[2][4] = {};
  const int np = Kd >> 6;

  auto STAGE = [&](int p, int buf) {
    int k0 = p << 6;
#pragma unroll
    for (int i = 0; i < 2; ++i) {
      int row = wave * 16 + i * 8 + lrow;
      int sc = lch ^ (row & 7);
      gload_lds16(A + (size_t)(m0 + row) * Kd + k0 + sc * 8, &sA[buf][(wave * 16 + i * 8) * 64]);
    }
#pragma unroll
    for (int i = 0; i < 2; ++i) {
      int row = wave * 16 + i * 8 + lrow;
      int sc = lch ^ (row & 7);
      gload_lds16(W + (size_t)(n0 + row) * Kd + k0 + sc * 8, &sB[buf][(wave * 16 + i * 8) * 64]);
    }
  };
  auto COMPUTE = [&](int buf) {
#pragma unroll
    for (int kk = 0; kk < 2; ++kk) {
      bf16x8 af[2], bfr[4];
#pragma unroll
      for (int mi = 0; mi < 2; ++mi) {
        int row = wr * 32 + mi * 16 + lc;
        int chunk = (kk * 4 + l4) ^ lc7;
        af[mi] = __builtin_bit_cast(bf16x8, *(const u16x8*)(&sA[buf][row * 64 + chunk * 8]));
      }
#pragma unroll
      for (int ni = 0; ni < 4; ++ni) {
        int row = wcc * 64 + ni * 16 + lc;
        int chunk = (kk * 4 + l4) ^ lc7;
        bfr[ni] = __builtin_bit_cast(bf16x8, *(const u16x8*)(&sB[buf][row * 64 + chunk * 8]));
      }
      __builtin_amdgcn_s_setprio(1);
#pragma unroll
      for (int mi = 0; mi < 2; ++mi)
#pragma unroll
        for (int ni = 0; ni < 4; ++ni)
          acc[mi][ni] = __builtin_amdgcn_mfma_f32_16x16x32_bf16(af[mi], bfr[ni], acc[mi][ni], 0, 0, 0);
      __builtin_amdgcn_s_setprio(0);
    }
  };

  STAGE(0, 0);
  for (int p = 0; p < np; ++p) {
    int cur = p & 1;
    if (p < np - 1) {
      STAGE(p + 1, cur ^ 1);
      asm volatile("s_waitcnt vmcnt(4)" ::: "memory");
    } else {
      asm volatile("s_waitcnt vmcnt(0)" ::: "memory");
    }
    __builtin_amdgcn_sched_barrier(0);
    __builtin_amdgcn_s_barrier();
    __builtin_amdgcn_sched_barrier(0);
    COMPUTE(cur);
    __builtin_amdgcn_sched_barrier(0);
    __builtin_amdgcn_s_barrier();
  }

#pragma unroll
  for (int ni = 0; ni < 4; ++ni) {
    float s = 0.f, q = 0.f;
    int col = wcc * 64 + ni * 16 + lc;
#pragma unroll
    for (int mi = 0; mi < 2; ++mi)
#pragma unroll
      for (int j = 0; j < 4; ++j) {
        int n = m0 + wr * 32 + mi * 16 + l4 * 4 + j;
        unsigned short u = f2bfu(acc[mi][ni][j]);
        if (n < M) C[(size_t)n * Nc + n0 + col] = u;
        float v = bfu2f(u);
        s += v; q += v * v;
      }
    s += __shfl_xor(s, 16); s += __shfl_xor(s, 32);
    q += __shfl_xor(q, 16); q += __shfl_xor(q, 32);
    if (lane < 16) {
      sStat[wave][0][col] = s;
      sStat[wave][1][col] = q;
    }
  }
  __syncthreads();
  if (t < 128) {
    int wcs = t >> 6;
    float s = 0.f, q = 0.f;
#pragma unroll
    for (int g = 0; g < 4; ++g) {
      s += sStat[g * 2 + wcs][0][t];
      q += sStat[g * 2 + wcs][1][t];
    }
    partials[(size_t)rowt * (2 * Nc) + n0 + t] = s;
    partials[(size_t)rowt * (2 * Nc) + Nc + n0 + t] = q;
  }
}

// --- FUSED octree | shortcut GEMM, INTERLEAVED dispatch (1 oct per 4 sc) ----
__global__ __launch_bounds__(512, 4) void octree_sc(
    const unsigned short* __restrict__ c1, const int* __restrict__ neigh,
    const unsigned short* __restrict__ w3t, unsigned short* __restrict__ c2p,
    float* __restrict__ part12,
    const unsigned short* __restrict__ h, const unsigned short* __restrict__ wc,
    unsigned short* __restrict__ scp, float* __restrict__ partsc,
    int M, int MTO) {
  __shared__ unsigned short sA[2][128 * 64];
  __shared__ unsigned short sB[2][128 * 64];
  __shared__ union {
    unsigned short nidx[128 * 27];
    float stat[8][2][128];
  } u;
  int t = threadIdx.x, wave = t >> 6, lane = t & 63;
  int wr = wave >> 1, wcc = wave & 1;
  int l4 = lane >> 4, lc = lane & 15, lc7 = lc & 7;
  int lrow = lane >> 3, lch = lane & 7;
  f32x4 acc[2][4] = {};
  int bid = blockIdx.x;
  bool isOct = (bid % 5) == 4;   // interleave: every 5th block is octree

  if (isOct) {
    int rowt = bid / 5;
    int m0 = rowt * 128;
    for (int i = t; i < 128 * 27; i += 512) {
      int row = i / 27;
      u.nidx[i] = (unsigned short)((m0 + row < M) ? neigh[(size_t)m0 * 27 + i] : M);
    }
    __syncthreads();

    auto STAGE = [&](int p, int buf) {
      int k = p >> 1, c0 = (p & 1) << 6;
#pragma unroll
      for (int i = 0; i < 2; ++i) {
        int row = wave * 16 + i * 8 + lrow;
        int nr = u.nidx[row * 27 + k];
        int sc = lch ^ (row & 7);
        gload_lds16(c1 + ((size_t)nr << 7) + c0 + sc * 8, &sA[buf][(wave * 16 + i * 8) * 64]);
      }
      const unsigned short* wk = w3t + ((size_t)k << 14);
#pragma unroll
      for (int i = 0; i < 2; ++i) {
        int row = wave * 16 + i * 8 + lrow;
        int sc = lch ^ (row & 7);
        gload_lds16(wk + ((size_t)row << 7) + c0 + sc * 8, &sB[buf][(wave * 16 + i * 8) * 64]);
      }
    };
    auto COMPUTE = [&](int buf) {
#pragma unroll
      for (int kk = 0; kk < 2; ++kk) {
        bf16x8 af[2], bfr[4];
#pragma unroll
        for (int mi = 0; mi < 2; ++mi) {
          int row = wr * 32 + mi * 16 + lc;
          int chunk = (kk * 4 + l4) ^ lc7;
          af[mi] = __builtin_bit_cast(bf16x8, *(const u16x8*)(&sA[buf][row * 64 + chunk * 8]));
        }
#pragma unroll
        for (int ni = 0; ni < 4; ++ni) {
          int row = wcc * 64 + ni * 16 + lc;
          int chunk = (kk * 4 + l4) ^ lc7;
          bfr[ni] = __builtin_bit_cast(bf16x8, *(const u16x8*)(&sB[buf][row * 64 + chunk * 8]));
        }
        __builtin_amdgcn_s_setprio(1);
#pragma unroll
        for (int mi = 0; mi < 2; ++mi)
#pragma unroll
          for (int ni = 0; ni < 4; ++ni)
            acc[mi][ni] = __builtin_amdgcn_mfma_f32_16x16x32_bf16(af[mi], bfr[ni], acc[mi][ni], 0, 0, 0);
        __builtin_amdgcn_s_setprio(0);
      }
    };

    STAGE(0, 0);
    for (int p = 0; p < 54; ++p) {
      int cur = p & 1;
      if (p < 53) {
        STAGE(p + 1, cur ^ 1);
        asm volatile("s_waitcnt vmcnt(4)" ::: "memory");
      } else {
        asm volatile("s_waitcnt vmcnt(0)" ::: "memory");
      }
      __builtin_amdgcn_sched_barrier(0);
      __builtin_amdgcn_s_barrier();
      __builtin_amdgcn_sched_barrier(0);
      COMPUTE(cur);
      __builtin_amdgcn_sched_barrier(0);
      __builtin_amdgcn_s_barrier();
    }

#pragma unroll
    for (int ni = 0; ni < 4; ++ni) {
      float s = 0.f, q = 0.f;
      int col = wcc * 64 + ni * 16 + lc;
#pragma unroll
      for (int mi = 0; mi < 2; ++mi)
#pragma unroll
        for (int j = 0; j < 4; ++j) {
          int n = m0 + wr * 32 + mi * 16 + l4 * 4 + j;
          unsigned short uo = f2bfu(acc[mi][ni][j]);
          if (n < M) c2p[(size_t)n * 128 + col] = uo;
          float v = bfu2f(uo);
          s += v; q += v * v;
        }
      s += __shfl_xor(s, 16); s += __shfl_xor(s, 32);
      q += __shfl_xor(q, 16); q += __shfl_xor(q, 32);
      if (lane < 16) {
        u.stat[wave][0][col] = s;
        u.stat[wave][1][col] = q;
      }
    }
    __syncthreads();
    if (t < 128) {
      int wcs = t >> 6;
      float s = 0.f, q = 0.f;
#pragma unroll
      for (int g = 0; g < 4; ++g) {
        s += u.stat[g * 2 + wcs][0][t];
        q += u.stat[g * 2 + wcs][1][t];
      }
      part12[(size_t)rowt * 256 + t] = s;
      part12[(size_t)rowt * 256 + 128 + t] = q;
    }
    return;
  }

  // shortcut GEMM path
  {
    int scIdx = (bid / 5) * 4 + (bid % 5);
    int flat = xcd_swz(scIdx, 4 * MTO);
    int n0 = (flat & 3) * 128;
    int rowt = flat >> 2;
    int m0 = rowt * 128;

    auto STAGE = [&](int p, int buf) {
      int k0 = p << 6;
#pragma unroll
      for (int i = 0; i < 2; ++i) {
        int row = wave * 16 + i * 8 + lrow;
        int sc = lch ^ (row & 7);
        gload_lds16(h + (size_t)(m0 + row) * 256 + k0 + sc * 8, &sA[buf][(wave * 16 + i * 8) * 64]);
      }
#pragma unroll
      for (int i = 0; i < 2; ++i) {
        int row = wave * 16 + i * 8 + lrow;
        int sc = lch ^ (row & 7);
        gload_lds16(wc + (size_t)(n0 + row) * 256 + k0 + sc * 8, &sB[buf][(wave * 16 + i * 8) * 64]);
      }
    };
    auto COMPUTE = [&](int buf) {
#pragma unroll
      for (int kk = 0; kk < 2; ++kk) {
        bf16x8 af[2], bfr[4];
#pragma unroll
        for (int mi = 0; mi < 2; ++mi) {
          int row = wr * 32 + mi * 16 + lc;
          int chunk = (kk * 4 + l4) ^ lc7;
          af[mi] = __builtin_bit_cast(bf16x8, *(const u16x8*)(&sA[buf][row * 64 + chunk * 8]));
        }
#pragma unroll
        for (int ni = 0; ni < 4; ++ni) {
          int row = wcc * 64 + ni * 16 + lc;
          int chunk = (kk * 4 + l4) ^ lc7;
          bfr[ni] = __builtin_bit_cast(bf16x8, *(const u16x8*)(&sB[buf][row * 64 + chunk * 8]));
        }
        __builtin_amdgcn_s_setprio(1);
#pragma unroll
        for (int mi = 0; mi < 2; ++mi)
#pragma unroll
          for (int ni = 0; ni < 4; ++ni)
            acc[mi][ni] = __builtin_amdgcn_mfma_f32_16x16x32_bf16(af[mi], bfr[ni], acc[mi][ni], 0, 0, 0);
        __builtin_amdgcn_s_setprio(0);
      }
    };

    STAGE(0, 0);
    for (int p = 0; p < 4; ++p) {
      int cur = p & 1;
      if (p < 3) {
        STAGE(p + 1, cur ^ 1);
        asm volatile("s_waitcnt vmcnt(4)" ::: "memory");
      } else {
        asm volatile("s_waitcnt vmcnt(0)" ::: "memory");
      }
      __builtin_amdgcn_sched_barrier(0);
      __builtin_amdgcn_s_barrier();
      __builtin_amdgcn_sched_barrier(0);
      COMPUTE(cur);
      __builtin_amdgcn_sched_barrier(0);
      __builtin_amdgcn_s_barrier();
    }

#pragma unroll
    for (int ni = 0; ni < 4; ++ni) {
      float s = 0.f, q = 0.f;
      int col = wcc * 64 + ni * 16 + lc;
#pragma unroll
      for (int mi = 0; mi < 2; ++mi)
#pragma unroll
        for (int j = 0; j < 4; ++j) {
          int n = m0 + wr * 32 + mi * 16 + l4 * 4 + j;
          unsigned short uo = f2bfu(acc[mi][ni][j]);
          if (n < M) scp[(size_t)n * 512 + n0 + col] = uo;
          float v = bfu2f(uo);
          s += v; q += v * v;
        }
      s += __shfl_xor(s, 16); s += __shfl_xor(s, 32);
      q += __shfl_xor(q, 16); q += __shfl_xor(q, 32);
      if (lane < 16) {
        u.stat[wave][0][col] = s;
        u.stat[wave][1][col] = q;
      }
    }
    __syncthreads();
    if (t < 128) {
      int wcs = t >> 6;
      float s = 0.f, q = 0.f;
#pragma unroll
      for (int g = 0; g < 4; ++g) {
        s += u.stat[g * 2 + wcs][0][t];
        q += u.stat[g * 2 + wcs][1][t];
      }
      partsc[(size_t)rowt * 1024 + n0 + t] = s;
      partsc[(size_t)rowt * 1024 + 512 + n0 + t] = q;
    }
  }
}

// --- reduce partials -> scale/shift, one block per channel ------------------
__global__ __launch_bounds__(256) void bn_finalize(
    const float* __restrict__ partials, int nb, int C, int M,
    const float* __restrict__ g, const float* __restrict__ bt,
    float* __restrict__ ss) {
  int c = blockIdx.x;
  int t = threadIdx.x;
  float s = 0.f, s2 = 0.f;
  for (int b = t; b < nb; b += 256) {
    s += partials[(size_t)b * 2 * C + c];
    s2 += partials[(size_t)b * 2 * C + C + c];
  }
#pragma unroll
  for (int off = 32; off >= 1; off >>= 1) {
    s += __shfl_xor(s, off);
    s2 += __shfl_xor(s2, off);
  }
  __shared__ float sh[4][2];
  int wave = t >> 6, lane = t & 63;
  if (lane == 0) { sh[wave][0] = s; sh[wave][1] = s2; }
  __syncthreads();
  if (t == 0) {
    s = sh[0][0] + sh[1][0] + sh[2][0] + sh[3][0];
    s2 = sh[0][1] + sh[1][1] + sh[2][1] + sh[3][1];
    float mean = s / (float)M;
    float var = s2 / (float)M - mean * mean;
    float sc = g[c] * rsqrtf(var + 1e-5f);
    ss[c] = sc;
    ss[C + c] = bt[c] - mean * sc;
  }
}

// --- elementwise BN + ReLU, bf16 in/out; zero-pads rows [M, Mpad) -----------
__global__ __launch_bounds__(256) void bnrelu(
    const unsigned short* __restrict__ P, const float* __restrict__ ss,
    unsigned short* __restrict__ Aout, int total, int total2, int Cmask) {
  int i = (blockIdx.x * 256 + threadIdx.x) * 8;
  if (i >= total2) return;
  u16x8 o = {0, 0, 0, 0, 0, 0, 0, 0};
  if (i < total) {
    u16x8 v = *(const u16x8*)(P + i);
    int c0 = i & Cmask;
    int C = Cmask + 1;
#pragma unroll
    for (int j = 0; j < 8; ++j) {
      float f = bfu2f(v[j]) * ss[c0 + j] + ss[C + c0 + j];
      o[j] = f2bfu(fmaxf(f, 0.f));
    }
  }
  *(u16x8*)(Aout + i) = o;
}

// --- BN+ReLU for c2, writing BOTH wA [Mpad][128] and wA_T [128][Mpad] -------
__global__ __launch_bounds__(256) void bnrelu2T(
    const unsigned short* __restrict__ P, const float* __restrict__ ss,
    unsigned short* __restrict__ wA, unsigned short* __restrict__ wAT,
    int M, int Mpad) {
  __shared__ unsigned short tp[128][72];   // [c][r], row stride 144B (16B-aligned)
  int t = threadIdx.x;
  int n0 = blockIdx.x * 64;
  int r = t >> 2, c0q = (t & 3) * 32;
#pragma unroll
  for (int q = 0; q < 4; ++q) {
    int ch = c0q + q * 8;
    u16x8 o = {0, 0, 0, 0, 0, 0, 0, 0};
    if (n0 + r < M) {
      u16x8 v = *(const u16x8*)(P + (size_t)(n0 + r) * 128 + ch);
#pragma unroll
      for (int j = 0; j < 8; ++j) {
        float f = bfu2f(v[j]) * ss[ch + j] + ss[128 + ch + j];
        o[j] = f2bfu(fmaxf(f, 0.f));
      }
    }
    *(u16x8*)(wA + (size_t)(n0 + r) * 128 + ch) = o;
#pragma unroll
    for (int j = 0; j < 8; ++j) tp[ch + j][r] = o[j];
  }
  __syncthreads();
  int c = t >> 1, half = t & 1;
#pragma unroll
  for (int i = 0; i < 4; ++i) {
    u16x8 v = *(const u16x8*)(&tp[c][half * 32 + i * 8]);
    *(u16x8*)(wAT + (size_t)c * Mpad + n0 + half * 32 + i * 8) = v;
  }
}

// --- split-K Gram: g2part[b] = (wAT-chunk) @ (wAT-chunk)^T  [128][128] ------
__global__ __launch_bounds__(512, 4) void gram2(
    const unsigned short* __restrict__ wAT, float* __restrict__ g2part,
    int Mpad, int phasesTotal) {
  __shared__ unsigned short sX[2][128 * 64];
  int t = threadIdx.x, wave = t >> 6, lane = t & 63;
  int wr = wave >> 2, wcc = wave & 3;          // 2x4 wave grid: 64x32 per wave
  int l4 = lane >> 4, lc = lane & 15, lc7 = lc & 7;
  int lrow = lane >> 3, lch = lane & 7;
  int p0 = blockIdx.x * 4;
  int pend = min(phasesTotal, p0 + 4);
  f32x4 acc[4][2] = {};

  auto STAGE = [&](int p, int buf) {
#pragma unroll
    for (int i = 0; i < 2; ++i) {
      int row = wave * 16 + i * 8 + lrow;
      int sc = lch ^ (row & 7);
      gload_lds16(wAT + (size_t)row * Mpad + p * 64 + sc * 8, &sX[buf][(wave * 16 + i * 8) * 64]);
    }
  };
  auto COMPUTE = [&](int buf) {
#pragma unroll
    for (int kk = 0; kk < 2; ++kk) {
      bf16x8 af[4], bfr[2];
#pragma unroll
      for (int mi = 0; mi < 4; ++mi) {
        int row = wr * 64 + mi * 16 + lc;
        int chunk = (kk * 4 + l4) ^ lc7;
        af[mi] = __builtin_bit_cast(bf16x8, *(const u16x8*)(&sX[buf][row * 64 + chunk * 8]));
      }
#pragma unroll
      for (int ni = 0; ni < 2; ++ni) {
        int row = wcc * 32 + ni * 16 + lc;
        int chunk = (kk * 4 + l4) ^ lc7;
        bfr[ni] = __builtin_bit_cast(bf16x8, *(const u16x8*)(&sX[buf][row * 64 + chunk * 8]));
      }
#pragma unroll
      for (int mi = 0; mi < 4; ++mi)
#pragma unroll
        for (int ni = 0; ni < 2; ++ni)
          acc[mi][ni] = __builtin_amdgcn_mfma_f32_16x16x32_bf16(af[mi], bfr[ni], acc[mi][ni], 0, 0, 0);
    }
  };

  STAGE(p0, 0);
  for (int p = p0; p < pend; ++p) {
    int cur = (p - p0) & 1;
    if (p + 1 < pend) {
      STAGE(p + 1, cur ^ 1);
      asm volatile("s_waitcnt vmcnt(2)" ::: "memory");
    } else {
      asm volatile("s_waitcnt vmcnt(0)" ::: "memory");
    }
    __builtin_amdgcn_sched_barrier(0);
    __builtin_amdgcn_s_barrier();
    __builtin_amdgcn_sched_barrier(0);
    COMPUTE(cur);
    __builtin_amdgcn_sched_barrier(0);
    __builtin_amdgcn_s_barrier();
  }

  float* outp = g2part + (size_t)blockIdx.x * 16384;
#pragma unroll
  for (int mi = 0; mi < 4; ++mi)
#pragma unroll
    for (int ni = 0; ni < 2; ++ni) {
      int col = wcc * 32 + ni * 16 + lc;
#pragma unroll
      for (int j = 0; j < 4; ++j) {
        int row = wr * 64 + mi * 16 + l4 * 4 + j;
        outp[row * 128 + col] = acc[mi][ni][j];
      }
    }
}

// --- reduce G2 partials + row-sums of wAT (mean_c2 raw sums) ----------------
__global__ __launch_bounds__(256) void reduce_mean(
    const float* __restrict__ g2part, int nk, float* __restrict__ G2,
    const unsigned short* __restrict__ wAT, int Mpad, float* __restrict__ meansum) {
  int b = blockIdx.x, t = threadIdx.x;
  if (b < 64) {
    int e = b * 256 + t;
    float s = 0.f;
    for (int k = 0; k < nk; ++k) s += g2part[(size_t)k * 16384 + e];
    G2[e] = s;
    return;
  }
  int r = b - 64;   // 0..127
  float s = 0.f;
  for (int cc = t * 8; cc < Mpad; cc += 2048) {
    u16x8 v = *(const u16x8*)(wAT + (size_t)r * Mpad + cc);
#pragma unroll
    for (int j = 0; j < 8; ++j) s += bfu2f(v[j]);
  }
#pragma unroll
  for (int off = 32; off >= 1; off >>= 1) s += __shfl_xor(s, off);
  __shared__ float sh[4];
  int wave = t >> 6, lane = t & 63;
  if (lane == 0) sh[wave] = s;
  __syncthreads();
  if (t == 0) meansum[r] = sh[0] + sh[1] + sh[2] + sh[3];
}

// --- quadratic-form BN3 stats + pre-scaled weights + diag(ssc) build --------
// var_j = (w_j . G2 . w_j)/M - m_j^2 ; m_j = (meansum . w_j)/M
__global__ __launch_bounds__(128) void qf_all(
    const float* __restrict__ G2, const float* __restrict__ meansum,
    const unsigned short* __restrict__ w1b, const float* __restrict__ g1b,
    const float* __restrict__ b1b, const float* __restrict__ sssc,
    float* __restrict__ sh3, unsigned short* __restrict__ w1bS,
    unsigned short* __restrict__ Ddiag, int M) {
  int j = blockIdx.x, i = threadIdx.x;
  __shared__ float wsh[128];
  __shared__ float red[4];
  float wi = bfu2f(w1b[j * 128 + i]);
  wsh[i] = wi;
  __syncthreads();
  float v = 0.f;
  for (int l = 0; l < 128; ++l) v += G2[l * 128 + i] * wsh[l];   // G2 symmetric
  float a = wi * v;
  float bmy = meansum[i] * wi;
#pragma unroll
  for (int off = 32; off >= 1; off >>= 1) {
    a += __shfl_xor(a, off);
    bmy += __shfl_xor(bmy, off);
  }
  int wv = i >> 6, ln = i & 63;
  if (ln == 0) { red[wv * 2] = a; red[wv * 2 + 1] = bmy; }
  __syncthreads();
  float qf = red[0] + red[2];
  float ms = red[1] + red[3];
  float m3 = ms / (float)M;
  float var = qf / (float)M - m3 * m3;
  float s3 = g1b[j] * rsqrtf(var + 1e-5f);
  if (i == 0) sh3[j] = b1b[j] - m3 * s3;
  w1bS[j * 128 + i] = f2bfu(wi * s3);
  Ddiag[j * 128 + i] = (i == (j & 127)) ? f2bfu(sssc[j]) : (unsigned short)0;
}

// --- FUSED final: acc = c2@w1bS^T (K=128) + scp@diag(ssc) (K=128) ;
//     out = relu(acc + sh3 + shift_sc), transposed fp32 write ---------------
__global__ __launch_bounds__(512, 2) void final_fused(
    const unsigned short* __restrict__ wA, const unsigned short* __restrict__ w1bS,
    const unsigned short* __restrict__ scp, const unsigned short* __restrict__ Ddiag,
    const float* __restrict__ sh3, const float* __restrict__ sssc,
    float* __restrict__ out, int M) {
  __shared__ union {
    struct { unsigned short A[2][128 * 64]; unsigned short B[2][128 * 64]; } m;
    float tp[64][132];
  } s;
  int t = threadIdx.x, wave = t >> 6, lane = t & 63;
  int wr = wave >> 1, wcc = wave & 1;
  int l4 = lane >> 4, lc = lane & 15, lc7 = lc & 7;
  int lrow = lane >> 3, lch = lane & 7;
  int flat = xcd_swz(blockIdx.x, gridDim.x);
  int n0 = (flat & 3) * 128;
  int rowt = flat >> 2;
  int m0 = rowt * 128;
  f32x4 acc[2][4] = {};

  auto STAGE = [&](int p, int buf) {
#pragma unroll
    for (int i = 0; i < 2; ++i) {
      int row = wave * 16 + i * 8 + lrow;
      int sc = lch ^ (row & 7);
      const unsigned short* ap;
      const unsigned short* bp;
      if (p < 2) {
        int k0 = p * 64;
        ap = wA + (size_t)(m0 + row) * 128 + k0 + sc * 8;
        bp = w1bS + (size_t)(n0 + row) * 128 + k0 + sc * 8;
      } else {
        int k0 = (p - 2) * 64;
        ap = scp + (size_t)(m0 + row) * 512 + n0 + k0 + sc * 8;
        bp = Ddiag + (size_t)(n0 + row) * 128 + k0 + sc * 8;
      }
      gload_lds16(ap, &s.m.A[buf][(wave * 16 + i * 8) * 64]);
      gload_lds16(bp, &s.m.B[buf][(wave * 16 + i * 8) * 64]);
    }
  };
  auto COMPUTE = [&](int buf) {
#pragma unroll
    for (int kk = 0; kk < 2; ++kk) {
      bf16x8 af[2], bfr[4];
#pragma unroll
      for (int mi = 0; mi < 2; ++mi) {
        int row = wr * 32 + mi * 16 + lc;
        int chunk = (kk * 4 + l4) ^ lc7;
        af[mi] = __builtin_bit_cast(bf16x8, *(const u16x8*)(&s.m.A[buf][row * 64 + chunk * 8]));
      }
#pragma unroll
      for (int ni = 0; ni < 4; ++ni) {
        int row = wcc * 64 + ni * 16 + lc;
        int chunk = (kk * 4 + l4) ^ lc7;
        bfr[ni] = __builtin_bit_cast(bf16x8, *(const u16x8*)(&s.m.B[buf][row * 64 + chunk * 8]));
      }
      __builtin_amdgcn_s_setprio(1);
#pragma unroll
      for (int mi = 0; mi < 2; ++mi)
#pragma unroll
        for (int ni = 0; ni < 4; ++ni)
          acc[mi][ni] = __builtin_amdgcn_mfma_f32_16x16x32_bf16(af[mi], bfr[ni], acc[mi][ni], 0, 0, 0);
      __builtin_amdgcn_s_setprio(0);
    }
  };

  STAGE(0, 0);
  for (int p = 0; p < 4; ++p) {
    int cur = p & 1;
    if (p < 3) {
      STAGE(p + 1, cur ^ 1);
      asm volatile("s_waitcnt vmcnt(4)" ::: "memory");
    } else {
      asm volatile("s_waitcnt vmcnt(0)" ::: "memory");
    }
    __builtin_amdgcn_sched_barrier(0);
    __builtin_amdgcn_s_barrier();
    __builtin_amdgcn_sched_barrier(0);
    COMPUTE(cur);
    __builtin_amdgcn_sched_barrier(0);
    __builtin_amdgcn_s_barrier();
  }

  // epilogue: shift+relu, LDS transpose (64 cols per pass), coalesced store
#pragma unroll
  for (int hf = 0; hf < 2; ++hf) {
    if (wcc == hf) {
#pragma unroll
      for (int ni = 0; ni < 4; ++ni) {
        int col_l = ni * 16 + lc;
        int cg = n0 + hf * 64 + col_l;
        float sh = sh3[cg] + sssc[512 + cg];
#pragma unroll
        for (int mi = 0; mi < 2; ++mi) {
          f32x4 o;
#pragma unroll
          for (int j = 0; j < 4; ++j) o[j] = fmaxf(acc[mi][ni][j] + sh, 0.f);
          *(f32x4*)(&s.tp[col_l][wr * 32 + mi * 16 + l4 * 4]) = o;
        }
      }
    }
    __syncthreads();
    {
      int col_l = t >> 3, seg = t & 7;
      int cg = n0 + hf * 64 + col_l;
      int nb = m0 + seg * 16;
      f32x4 r0 = *(const f32x4*)(&s.tp[col_l][seg * 16 + 0]);
      f32x4 r1 = *(const f32x4*)(&s.tp[col_l][seg * 16 + 4]);
      f32x4 r2 = *(const f32x4*)(&s.tp[col_l][seg * 16 + 8]);
      f32x4 r3 = *(const f32x4*)(&s.tp[col_l][seg * 16 + 12]);
      if (nb + 16 <= M) {
        f32x4* po = (f32x4*)(out + (size_t)cg * M + nb);
        po[0] = r0; po[1] = r1; po[2] = r2; po[3] = r3;
      } else {
        float rr[16];
        *(f32x4*)&rr[0] = r0; *(f32x4*)&rr[4] = r1;
        *(f32x4*)&rr[8] = r2; *(f32x4*)&rr[12] = r3;
        for (int e = 0; e < 16; ++e)
          if (nb + e < M) out[(size_t)cg * M + nb + e] = rr[e];
      }
    }
    __syncthreads();
  }
}

extern "C" void kernel_launch(void* const* d_in, const int* in_sizes, int n_in,
                              void* d_out, int out_size, void* d_ws, size_t ws_size,
                              hipStream_t stream) {
  const float* x   = (const float*)d_in[0];
  const int* neigh = (const int*)d_in[1];
  const float* W1a = (const float*)d_in[2];
  const float* g1a = (const float*)d_in[3];
  const float* b1a = (const float*)d_in[4];
  const float* W3  = (const float*)d_in[5];
  const float* g3  = (const float*)d_in[6];
  const float* b3  = (const float*)d_in[7];
  const float* W1b = (const float*)d_in[8];
  const float* g1b = (const float*)d_in[9];
  const float* b1b = (const float*)d_in[10];
  const float* Wc  = (const float*)d_in[11];
  const float* gc  = (const float*)d_in[12];
  const float* bc  = (const float*)d_in[13];
  float* out = (float*)d_out;

  const int M = in_sizes[1] / 27;          // 60000
  const int MT = (M + 63) / 64;            // 938
  const int MTO = (M + 127) / 128;         // 469
  const int Mpad = MT * 64;                // 60032

  char* ws = (char*)d_ws;
  unsigned short* h   = (unsigned short*)(ws + 0);           // [Mpad][256]
  unsigned short* wA  = (unsigned short*)(ws + 30736384);    // [Mpad][128]
  unsigned short* wP  = (unsigned short*)(ws + 46104576);    // [M][128]
  unsigned short* scp = (unsigned short*)(ws + 122904576);   // [M][512] (+pad slack)
  unsigned short* w1a = (unsigned short*)(ws + 184344576);
  unsigned short* w3t = (unsigned short*)(ws + 184410112);
  unsigned short* w1b = (unsigned short*)(ws + 185294848);
  unsigned short* wc  = (unsigned short*)(ws + 185425920);
  float* ss1  = (float*)(ws + 185688064);
  float* ss2  = (float*)(ws + 185692160);
  float* sssc = (float*)(ws + 185700352);

  // scratch inside the (now-unused) c3p region:
  const size_t O = 61464576;
  float* part1   = (float*)(ws + O);
  float* part12  = (float*)(ws + O + 1048576);
  float* partsc  = (float*)(ws + O + 2097152);
  float* g2part  = (float*)(ws + O + 4194304);     // <= 256*64KB
  unsigned short* wAT = (unsigned short*)(ws + O + 22020096);  // [128][Mpad]
  float* G2      = (float*)(ws + O + 39845888);    // 64 KB
  float* meansum = (float*)(ws + O + 39911424);    // 512 B
  float* sh3     = (float*)(ws + O + 39913472);    // 2 KB
  unsigned short* w1bS  = (unsigned short*)(ws + O + 39915520);  // 128 KB
  unsigned short* Ddiag = (unsigned short*)(ws + O + 40046592);  // 128 KB

  prep_transpose<<<432 + MT * 4, 256, 0, stream>>>(
      x, h, W1a, W3, W1b, Wc, w1a, w3t, w1b, wc, M, MT);

  const int total = M * 128, total2 = Mpad * 128;
  const int bnGrid = (total2 / 8 + 255) / 256;

  // c1 = relu(bn(h @ W1a^T))
  gemm128<<<MTO, 512, 0, stream>>>(h, w1a, wP, part1, M, 256, 128, 1);
  bn_finalize<<<128, 256, 0, stream>>>(part1, MTO, 128, M, g1a, b1a, ss1);
  bnrelu<<<bnGrid, 256, 0, stream>>>(wP, ss1, wA, total, total2, 127);

  // FUSED+interleaved: c2_pre = octree_conv(c1)  ||  sc_pre = h @ Wc^T
  octree_sc<<<5 * MTO, 512, 0, stream>>>(
      wA, neigh, w3t, wP, part12, h, wc, scp, partsc, M, MTO);
  bn_finalize<<<128, 256, 0, stream>>>(part12, MTO, 128, M, g3, b3, ss2);
  bn_finalize<<<512, 256, 0, stream>>>(partsc, MTO, 512, M, gc, bc, sssc);

  // c2 = relu(bn(c2_pre)) -> wA row-major + wAT transposed (for Gram)
  bnrelu2T<<<MT, 256, 0, stream>>>(wP, ss2, wA, wAT, M, Mpad);

  // G2 = c2^T c2 (split-K), mean_c2 sums, then BN3 stats via quadratic form
  const int phases = Mpad / 64;
  const int NK = (phases + 3) / 4;
  gram2<<<NK, 512, 0, stream>>>(wAT, g2part, Mpad, phases);
  reduce_mean<<<192, 256, 0, stream>>>(g2part, NK, G2, wAT, Mpad, meansum);
  qf_all<<<512, 128, 0, stream>>>(G2, meansum, w1b, g1b, b1b, sssc,
                                  sh3, w1bS, Ddiag, M);

  // out = relu( c2@w1bS^T + scp@diag(ssc) + sh3 + shift_sc ), transposed
  final_fused<<<4 * MTO, 512, 0, stream>>>(wA, w1bS, scp, Ddiag, sh3, sssc, out, M);
}

// Round 12
// 221.726 us; speedup vs baseline: 1.5622x; 1.5622x over previous
//
#include <hip/hip_runtime.h>

// ---------------------------------------------------------------------------
// OctreeResBlock on MI355X (gfx950), round 11:
// REVERT to the r10-measured 225.6us configuration (Gram chain and block
// interleave both regressed; one lever per round). One octree change:
// phase order half-OUTER (phases 0-26 read only c1 bytes [0,128), 27-53 the
// rest) -> L2 working set halves (15.4 -> 7.7 MB), one 128B line per gather.
// Plus: two post-octree bn_finalize launches merged into one dual launch.
// ---------------------------------------------------------------------------

typedef __bf16 bf16x8 __attribute__((ext_vector_type(8)));
typedef float f32x4 __attribute__((ext_vector_type(4)));
typedef unsigned short u16x8 __attribute__((ext_vector_type(8)));
typedef unsigned short u16x4 __attribute__((ext_vector_type(4)));

__device__ __forceinline__ unsigned short f2bfu(float f) {
  union { float f; unsigned u; } v; v.f = f;
  unsigned r = v.u + 0x7fffu + ((v.u >> 16) & 1u);   // round-to-nearest-even
  return (unsigned short)(r >> 16);
}
__device__ __forceinline__ float bfu2f(unsigned short s) {
  union { unsigned u; float f; } v; v.u = ((unsigned)s) << 16;
  return v.f;
}

// async global->LDS, 16B per lane; dest = wave-uniform base + lane*16
__device__ __forceinline__ void gload_lds16(const unsigned short* g, unsigned short* l) {
  __builtin_amdgcn_global_load_lds(
      (const __attribute__((address_space(1))) unsigned int*)(unsigned long long)g,
      (__attribute__((address_space(3))) unsigned int*)(unsigned int)(unsigned long long)l,
      16, 0, 0);
}

// bijective chunked XCD swizzle (m204)
__device__ __forceinline__ int xcd_swz(int bid, int nwg) {
  int q = nwg >> 3, r = nwg & 7;
  int xcd = bid & 7, idx = bid >> 3;
  int base = xcd < r ? xcd * (q + 1) : r * (q + 1) + (xcd - r) * q;
  return base + idx;
}

// --- fused: weights fp32->bf16 (+W3 transpose) | x transpose to h -----------
__global__ __launch_bounds__(256) void prep_transpose(
    const float* __restrict__ x, unsigned short* __restrict__ h,
    const float* __restrict__ W1a, const float* __restrict__ W3,
    const float* __restrict__ W1b, const float* __restrict__ Wc,
    unsigned short* __restrict__ w1a, unsigned short* __restrict__ w3t,
    unsigned short* __restrict__ w1b, unsigned short* __restrict__ wc,
    int M, int MT) {
  __shared__ float tile[64][65];
  int t = threadIdx.x;
  if (blockIdx.x < 432) {
    int i = blockIdx.x * 256 + t;
    for (; i < 442368; i += 432 * 256) {
      if (i < 32768)  w1a[i] = f2bfu(W1a[i]);
      if (i < 65536)  w1b[i] = f2bfu(W1b[i]);
      if (i < 131072) wc[i]  = f2bfu(Wc[i]);
      int k = i >> 14, rr = i & 16383;
      int d = rr >> 7, c = rr & 127;
      w3t[i] = f2bfu(W3[(k << 14) + (c << 7) + d]);
    }
    return;
  }
  int bid = blockIdx.x - 432;
  int n0 = (bid % MT) * 64, c0 = (bid / MT) * 64;
  int nl = t & 63;
#pragma unroll
  for (int i = 0; i < 16; ++i) {
    int cl = i * 4 + (t >> 6);
    int n = n0 + nl;
    tile[cl][nl] = (n < M) ? x[(size_t)(c0 + cl) * M + n] : 0.f;
  }
  __syncthreads();
  int cl = t & 63;
#pragma unroll
  for (int i = 0; i < 16; ++i) {
    int nl2 = i * 4 + (t >> 6);
    int n = n0 + nl2;
    h[(size_t)n * 256 + c0 + cl] = f2bfu(tile[cl][nl2]);   // pad rows get zeros
  }
}

// --- dense GEMM: C[M][Nc] = A[Mpad][Kd] * W[Nc][Kd]^T (r8 structure) --------
__global__ __launch_bounds__(512, 4) void gemm128(
    const unsigned short* __restrict__ A, const unsigned short* __restrict__ W,
    unsigned short* __restrict__ C, float* __restrict__ partials,
    int M, int Kd, int Nc, int ncol) {
  __shared__ unsigned short sA[2][128 * 64];
  __shared__ unsigned short sB[2][128 * 64];
  __shared__ float sStat[8][2][128];
  int t = threadIdx.x, wave = t >> 6, lane = t & 63;
  int flat = xcd_swz(blockIdx.x, gridDim.x);
  int n0 = (flat % ncol) * 128;
  int rowt = flat / ncol;
  int m0 = rowt * 128;
  int wr = wave >> 1, wcc = wave & 1;
  int l4 = lane >> 4, lc = lane & 15, lc7 = lc & 7;
  int lrow = lane >> 3, lch = lane & 7;
  f32x4 acc[2][4] = {};
  const int np = Kd >> 6;

  auto STAGE = [&](int p, int buf) {
    int k0 = p << 6;
#pragma unroll
    for (int i = 0; i < 2; ++i) {
      int row = wave * 16 + i * 8 + lrow;
      int sc = lch ^ (row & 7);
      gload_lds16(A + (size_t)(m0 + row) * Kd + k0 + sc * 8, &sA[buf][(wave * 16 + i * 8) * 64]);
    }
#pragma unroll
    for (int i = 0; i < 2; ++i) {
      int row = wave * 16 + i * 8 + lrow;
      int sc = lch ^ (row & 7);
      gload_lds16(W + (size_t)(n0 + row) * Kd + k0 + sc * 8, &sB[buf][(wave * 16 + i * 8) * 64]);
    }
  };
  auto COMPUTE = [&](int buf) {
#pragma unroll
    for (int kk = 0; kk < 2; ++kk) {
      bf16x8 af[2], bfr[4];
#pragma unroll
      for (int mi = 0; mi < 2; ++mi) {
        int row = wr * 32 + mi * 16 + lc;
        int chunk = (kk * 4 + l4) ^ lc7;
        af[mi] = __builtin_bit_cast(bf16x8, *(const u16x8*)(&sA[buf][row * 64 + chunk * 8]));
      }
#pragma unroll
      for (int ni = 0; ni < 4; ++ni) {
        int row = wcc * 64 + ni * 16 + lc;
        int chunk = (kk * 4 + l4) ^ lc7;
        bfr[ni] = __builtin_bit_cast(bf16x8, *(const u16x8*)(&sB[buf][row * 64 + chunk * 8]));
      }
      __builtin_amdgcn_s_setprio(1);
#pragma unroll
      for (int mi = 0; mi < 2; ++mi)
#pragma unroll
        for (int ni = 0; ni < 4; ++ni)
          acc[mi][ni] = __builtin_amdgcn_mfma_f32_16x16x32_bf16(af[mi], bfr[ni], acc[mi][ni], 0, 0, 0);
      __builtin_amdgcn_s_setprio(0);
    }
  };

  STAGE(0, 0);
  for (int p = 0; p < np; ++p) {
    int cur = p & 1;
    if (p < np - 1) {
      STAGE(p + 1, cur ^ 1);
      asm volatile("s_waitcnt vmcnt(4)" ::: "memory");
    } else {
      asm volatile("s_waitcnt vmcnt(0)" ::: "memory");
    }
    __builtin_amdgcn_sched_barrier(0);
    __builtin_amdgcn_s_barrier();
    __builtin_amdgcn_sched_barrier(0);
    COMPUTE(cur);
    __builtin_amdgcn_sched_barrier(0);
    __builtin_amdgcn_s_barrier();
  }

#pragma unroll
  for (int ni = 0; ni < 4; ++ni) {
    float s = 0.f, q = 0.f;
    int col = wcc * 64 + ni * 16 + lc;
#pragma unroll
    for (int mi = 0; mi < 2; ++mi)
#pragma unroll
      for (int j = 0; j < 4; ++j) {
        int n = m0 + wr * 32 + mi * 16 + l4 * 4 + j;
        unsigned short u = f2bfu(acc[mi][ni][j]);
        if (n < M) C[(size_t)n * Nc + n0 + col] = u;
        float v = bfu2f(u);
        s += v; q += v * v;
      }
    s += __shfl_xor(s, 16); s += __shfl_xor(s, 32);
    q += __shfl_xor(q, 16); q += __shfl_xor(q, 32);
    if (lane < 16) {
      sStat[wave][0][col] = s;
      sStat[wave][1][col] = q;
    }
  }
  __syncthreads();
  if (t < 128) {
    int wcs = t >> 6;
    float s = 0.f, q = 0.f;
#pragma unroll
    for (int g = 0; g < 4; ++g) {
      s += sStat[g * 2 + wcs][0][t];
      q += sStat[g * 2 + wcs][1][t];
    }
    partials[(size_t)rowt * (2 * Nc) + n0 + t] = s;
    partials[(size_t)rowt * (2 * Nc) + Nc + n0 + t] = q;
  }
}

// --- FUSED: octree conv (blocks [0,MTO)) | shortcut GEMM (rest) -------------
// Octree phase order: HALF-OUTER (p<27: c1 bytes [0,128); p>=27: [128,256))
// -> gather working set halves (7.7MB), one 128B L2 line per gather.
__global__ __launch_bounds__(512, 4) void octree_sc(
    const unsigned short* __restrict__ c1, const int* __restrict__ neigh,
    const unsigned short* __restrict__ w3t, unsigned short* __restrict__ c2p,
    float* __restrict__ part12,
    const unsigned short* __restrict__ h, const unsigned short* __restrict__ wc,
    unsigned short* __restrict__ scp, float* __restrict__ partsc,
    int M, int MTO) {
  __shared__ unsigned short sA[2][128 * 64];
  __shared__ unsigned short sB[2][128 * 64];
  __shared__ union {
    unsigned short nidx[128 * 27];
    float stat[8][2][128];
  } u;
  int t = threadIdx.x, wave = t >> 6, lane = t & 63;
  int wr = wave >> 1, wcc = wave & 1;
  int l4 = lane >> 4, lc = lane & 15, lc7 = lc & 7;
  int lrow = lane >> 3, lch = lane & 7;
  f32x4 acc[2][4] = {};

  if (blockIdx.x < (unsigned)MTO) {
    // ---------------- octree path ----------------
    int rowt = blockIdx.x;
    int m0 = rowt * 128;
    for (int i = t; i < 128 * 27; i += 512) {
      int row = i / 27;
      u.nidx[i] = (unsigned short)((m0 + row < M) ? neigh[(size_t)m0 * 27 + i] : M);
    }
    __syncthreads();

    auto STAGE = [&](int p, int buf) {
      int half = (p >= 27) ? 1 : 0;
      int k = p - half * 27;
      int c0 = half << 6;
#pragma unroll
      for (int i = 0; i < 2; ++i) {
        int row = wave * 16 + i * 8 + lrow;
        int nr = u.nidx[row * 27 + k];
        int sc = lch ^ (row & 7);
        gload_lds16(c1 + ((size_t)nr << 7) + c0 + sc * 8, &sA[buf][(wave * 16 + i * 8) * 64]);
      }
      const unsigned short* wk = w3t + ((size_t)k << 14);
#pragma unroll
      for (int i = 0; i < 2; ++i) {
        int row = wave * 16 + i * 8 + lrow;
        int sc = lch ^ (row & 7);
        gload_lds16(wk + ((size_t)row << 7) + c0 + sc * 8, &sB[buf][(wave * 16 + i * 8) * 64]);
      }
    };
    auto COMPUTE = [&](int buf) {
#pragma unroll
      for (int kk = 0; kk < 2; ++kk) {
        bf16x8 af[2], bfr[4];
#pragma unroll
        for (int mi = 0; mi < 2; ++mi) {
          int row = wr * 32 + mi * 16 + lc;
          int chunk = (kk * 4 + l4) ^ lc7;
          af[mi] = __builtin_bit_cast(bf16x8, *(const u16x8*)(&sA[buf][row * 64 + chunk * 8]));
        }
#pragma unroll
        for (int ni = 0; ni < 4; ++ni) {
          int row = wcc * 64 + ni * 16 + lc;
          int chunk = (kk * 4 + l4) ^ lc7;
          bfr[ni] = __builtin_bit_cast(bf16x8, *(const u16x8*)(&sB[buf][row * 64 + chunk * 8]));
        }
        __builtin_amdgcn_s_setprio(1);
#pragma unroll
        for (int mi = 0; mi < 2; ++mi)
#pragma unroll
          for (int ni = 0; ni < 4; ++ni)
            acc[mi][ni] = __builtin_amdgcn_mfma_f32_16x16x32_bf16(af[mi], bfr[ni], acc[mi][ni], 0, 0, 0);
        __builtin_amdgcn_s_setprio(0);
      }
    };

    STAGE(0, 0);
    for (int p = 0; p < 54; ++p) {
      int cur = p & 1;
      if (p < 53) {
        STAGE(p + 1, cur ^ 1);
        asm volatile("s_waitcnt vmcnt(4)" ::: "memory");
      } else {
        asm volatile("s_waitcnt vmcnt(0)" ::: "memory");
      }
      __builtin_amdgcn_sched_barrier(0);
      __builtin_amdgcn_s_barrier();
      __builtin_amdgcn_sched_barrier(0);
      COMPUTE(cur);
      __builtin_amdgcn_sched_barrier(0);
      __builtin_amdgcn_s_barrier();
    }

#pragma unroll
    for (int ni = 0; ni < 4; ++ni) {
      float s = 0.f, q = 0.f;
      int col = wcc * 64 + ni * 16 + lc;
#pragma unroll
      for (int mi = 0; mi < 2; ++mi)
#pragma unroll
        for (int j = 0; j < 4; ++j) {
          int n = m0 + wr * 32 + mi * 16 + l4 * 4 + j;
          unsigned short uo = f2bfu(acc[mi][ni][j]);
          if (n < M) c2p[(size_t)n * 128 + col] = uo;
          float v = bfu2f(uo);
          s += v; q += v * v;
        }
      s += __shfl_xor(s, 16); s += __shfl_xor(s, 32);
      q += __shfl_xor(q, 16); q += __shfl_xor(q, 32);
      if (lane < 16) {
        u.stat[wave][0][col] = s;
        u.stat[wave][1][col] = q;
      }
    }
    __syncthreads();
    if (t < 128) {
      int wcs = t >> 6;
      float s = 0.f, q = 0.f;
#pragma unroll
      for (int g = 0; g < 4; ++g) {
        s += u.stat[g * 2 + wcs][0][t];
        q += u.stat[g * 2 + wcs][1][t];
      }
      part12[(size_t)rowt * 256 + t] = s;
      part12[(size_t)rowt * 256 + 128 + t] = q;
    }
    return;
  }

  // ---------------- shortcut GEMM path (Kd=256, Nc=512, ncol=4) -------------
  {
    int flat = xcd_swz(blockIdx.x - MTO, gridDim.x - MTO);
    int n0 = (flat & 3) * 128;
    int rowt = flat >> 2;
    int m0 = rowt * 128;

    auto STAGE = [&](int p, int buf) {
      int k0 = p << 6;
#pragma unroll
      for (int i = 0; i < 2; ++i) {
        int row = wave * 16 + i * 8 + lrow;
        int sc = lch ^ (row & 7);
        gload_lds16(h + (size_t)(m0 + row) * 256 + k0 + sc * 8, &sA[buf][(wave * 16 + i * 8) * 64]);
      }
#pragma unroll
      for (int i = 0; i < 2; ++i) {
        int row = wave * 16 + i * 8 + lrow;
        int sc = lch ^ (row & 7);
        gload_lds16(wc + (size_t)(n0 + row) * 256 + k0 + sc * 8, &sB[buf][(wave * 16 + i * 8) * 64]);
      }
    };
    auto COMPUTE = [&](int buf) {
#pragma unroll
      for (int kk = 0; kk < 2; ++kk) {
        bf16x8 af[2], bfr[4];
#pragma unroll
        for (int mi = 0; mi < 2; ++mi) {
          int row = wr * 32 + mi * 16 + lc;
          int chunk = (kk * 4 + l4) ^ lc7;
          af[mi] = __builtin_bit_cast(bf16x8, *(const u16x8*)(&sA[buf][row * 64 + chunk * 8]));
        }
#pragma unroll
        for (int ni = 0; ni < 4; ++ni) {
          int row = wcc * 64 + ni * 16 + lc;
          int chunk = (kk * 4 + l4) ^ lc7;
          bfr[ni] = __builtin_bit_cast(bf16x8, *(const u16x8*)(&sB[buf][row * 64 + chunk * 8]));
        }
        __builtin_amdgcn_s_setprio(1);
#pragma unroll
        for (int mi = 0; mi < 2; ++mi)
#pragma unroll
          for (int ni = 0; ni < 4; ++ni)
            acc[mi][ni] = __builtin_amdgcn_mfma_f32_16x16x32_bf16(af[mi], bfr[ni], acc[mi][ni], 0, 0, 0);
        __builtin_amdgcn_s_setprio(0);
      }
    };

    STAGE(0, 0);
    for (int p = 0; p < 4; ++p) {
      int cur = p & 1;
      if (p < 3) {
        STAGE(p + 1, cur ^ 1);
        asm volatile("s_waitcnt vmcnt(4)" ::: "memory");
      } else {
        asm volatile("s_waitcnt vmcnt(0)" ::: "memory");
      }
      __builtin_amdgcn_sched_barrier(0);
      __builtin_amdgcn_s_barrier();
      __builtin_amdgcn_sched_barrier(0);
      COMPUTE(cur);
      __builtin_amdgcn_sched_barrier(0);
      __builtin_amdgcn_s_barrier();
    }

#pragma unroll
    for (int ni = 0; ni < 4; ++ni) {
      float s = 0.f, q = 0.f;
      int col = wcc * 64 + ni * 16 + lc;
#pragma unroll
      for (int mi = 0; mi < 2; ++mi)
#pragma unroll
        for (int j = 0; j < 4; ++j) {
          int n = m0 + wr * 32 + mi * 16 + l4 * 4 + j;
          unsigned short uo = f2bfu(acc[mi][ni][j]);
          if (n < M) scp[(size_t)n * 512 + n0 + col] = uo;
          float v = bfu2f(uo);
          s += v; q += v * v;
        }
      s += __shfl_xor(s, 16); s += __shfl_xor(s, 32);
      q += __shfl_xor(q, 16); q += __shfl_xor(q, 32);
      if (lane < 16) {
        u.stat[wave][0][col] = s;
        u.stat[wave][1][col] = q;
      }
    }
    __syncthreads();
    if (t < 128) {
      int wcs = t >> 6;
      float s = 0.f, q = 0.f;
#pragma unroll
      for (int g = 0; g < 4; ++g) {
        s += u.stat[g * 2 + wcs][0][t];
        q += u.stat[g * 2 + wcs][1][t];
      }
      partsc[(size_t)rowt * 1024 + n0 + t] = s;
      partsc[(size_t)rowt * 1024 + 512 + n0 + t] = q;
    }
  }
}

// --- reduce partials -> scale/shift, one block per channel ------------------
__global__ __launch_bounds__(256) void bn_finalize(
    const float* __restrict__ partials, int nb, int C, int M,
    const float* __restrict__ g, const float* __restrict__ bt,
    float* __restrict__ ss) {
  int c = blockIdx.x;
  int t = threadIdx.x;
  float s = 0.f, s2 = 0.f;
  for (int b = t; b < nb; b += 256) {
    s += partials[(size_t)b * 2 * C + c];
    s2 += partials[(size_t)b * 2 * C + C + c];
  }
#pragma unroll
  for (int off = 32; off >= 1; off >>= 1) {
    s += __shfl_xor(s, off);
    s2 += __shfl_xor(s2, off);
  }
  __shared__ float sh[4][2];
  int wave = t >> 6, lane = t & 63;
  if (lane == 0) { sh[wave][0] = s; sh[wave][1] = s2; }
  __syncthreads();
  if (t == 0) {
    s = sh[0][0] + sh[1][0] + sh[2][0] + sh[3][0];
    s2 = sh[0][1] + sh[1][1] + sh[2][1] + sh[3][1];
    float mean = s / (float)M;
    float var = s2 / (float)M - mean * mean;
    float sc = g[c] * rsqrtf(var + 1e-5f);
    ss[c] = sc;
    ss[C + c] = bt[c] - mean * sc;
  }
}

// --- dual bn_finalize: blocks [0,128) -> stage2 (C=128); rest -> sc (C=512) -
__global__ __launch_bounds__(256) void bn_finalize_dual(
    const float* __restrict__ part12, const float* __restrict__ partsc,
    int nb, int M,
    const float* __restrict__ g3, const float* __restrict__ b3,
    const float* __restrict__ gc, const float* __restrict__ bc,
    float* __restrict__ ss2, float* __restrict__ sssc) {
  const float* partials; const float* g; const float* bt; float* ss;
  int c, C;
  if (blockIdx.x < 128) {
    partials = part12; g = g3; bt = b3; ss = ss2; c = blockIdx.x; C = 128;
  } else {
    partials = partsc; g = gc; bt = bc; ss = sssc; c = blockIdx.x - 128; C = 512;
  }
  int t = threadIdx.x;
  float s = 0.f, s2 = 0.f;
  for (int b = t; b < nb; b += 256) {
    s += partials[(size_t)b * 2 * C + c];
    s2 += partials[(size_t)b * 2 * C + C + c];
  }
#pragma unroll
  for (int off = 32; off >= 1; off >>= 1) {
    s += __shfl_xor(s, off);
    s2 += __shfl_xor(s2, off);
  }
  __shared__ float sh[4][2];
  int wave = t >> 6, lane = t & 63;
  if (lane == 0) { sh[wave][0] = s; sh[wave][1] = s2; }
  __syncthreads();
  if (t == 0) {
    s = sh[0][0] + sh[1][0] + sh[2][0] + sh[3][0];
    s2 = sh[0][1] + sh[1][1] + sh[2][1] + sh[3][1];
    float mean = s / (float)M;
    float var = s2 / (float)M - mean * mean;
    float sc = g[c] * rsqrtf(var + 1e-5f);
    ss[c] = sc;
    ss[C + c] = bt[c] - mean * sc;
  }
}

// --- elementwise BN + ReLU, bf16 in/out; zero-pads rows [M, Mpad) -----------
__global__ __launch_bounds__(256) void bnrelu(
    const unsigned short* __restrict__ P, const float* __restrict__ ss,
    unsigned short* __restrict__ Aout, int total, int total2, int Cmask) {
  int i = (blockIdx.x * 256 + threadIdx.x) * 8;
  if (i >= total2) return;
  u16x8 o = {0, 0, 0, 0, 0, 0, 0, 0};
  if (i < total) {
    u16x8 v = *(const u16x8*)(P + i);
    int c0 = i & Cmask;
    int C = Cmask + 1;
#pragma unroll
    for (int j = 0; j < 8; ++j) {
      float f = bfu2f(v[j]) * ss[c0 + j] + ss[C + c0 + j];
      o[j] = f2bfu(fmaxf(f, 0.f));
    }
  }
  *(u16x8*)(Aout + i) = o;
}

// --- final: out[c][n] = relu(bn3(c3p) + bnsc(scp)), transposed fp32 write ---
__global__ __launch_bounds__(256) void final_out(
    const unsigned short* __restrict__ c3p, const unsigned short* __restrict__ scp,
    const float* __restrict__ ss3, const float* __restrict__ sssc,
    float* __restrict__ out, int M) {
  __shared__ float tile[64][129];
  int n0 = blockIdx.x * 64, c0 = blockIdx.y * 128;
  int t = threadIdx.x;
  int rowg = t >> 5, cg = (t & 31) * 4;
#pragma unroll
  for (int ps = 0; ps < 8; ++ps) {
    int nl = ps * 8 + rowg;
    int n = n0 + nl;
    float v0 = 0.f, v1 = 0.f, v2 = 0.f, v3 = 0.f;
    if (n < M) {
      u16x4 a = *(const u16x4*)(c3p + (size_t)n * 512 + c0 + cg);
      u16x4 b = *(const u16x4*)(scp + (size_t)n * 512 + c0 + cg);
      int c = c0 + cg;
      v0 = fmaxf(bfu2f(a[0]) * ss3[c + 0] + ss3[512 + c + 0] + bfu2f(b[0]) * sssc[c + 0] + sssc[512 + c + 0], 0.f);
      v1 = fmaxf(bfu2f(a[1]) * ss3[c + 1] + ss3[512 + c + 1] + bfu2f(b[1]) * sssc[c + 1] + sssc[512 + c + 1], 0.f);
      v2 = fmaxf(bfu2f(a[2]) * ss3[c + 2] + ss3[512 + c + 2] + bfu2f(b[2]) * sssc[c + 2] + sssc[512 + c + 2], 0.f);
      v3 = fmaxf(bfu2f(a[3]) * ss3[c + 3] + ss3[512 + c + 3] + bfu2f(b[3]) * sssc[c + 3] + sssc[512 + c + 3], 0.f);
    }
    tile[nl][cg + 0] = v0;
    tile[nl][cg + 1] = v1;
    tile[nl][cg + 2] = v2;
    tile[nl][cg + 3] = v3;
  }
  __syncthreads();
  int nl = t & 63, cq = t >> 6;
  int n = n0 + nl;
  if (n < M) {
#pragma unroll
    for (int i = 0; i < 32; ++i) {
      int cl = i * 4 + cq;
      out[(size_t)(c0 + cl) * M + n] = tile[nl][cl];
    }
  }
}

extern "C" void kernel_launch(void* const* d_in, const int* in_sizes, int n_in,
                              void* d_out, int out_size, void* d_ws, size_t ws_size,
                              hipStream_t stream) {
  const float* x   = (const float*)d_in[0];
  const int* neigh = (const int*)d_in[1];
  const float* W1a = (const float*)d_in[2];
  const float* g1a = (const float*)d_in[3];
  const float* b1a = (const float*)d_in[4];
  const float* W3  = (const float*)d_in[5];
  const float* g3  = (const float*)d_in[6];
  const float* b3  = (const float*)d_in[7];
  const float* W1b = (const float*)d_in[8];
  const float* g1b = (const float*)d_in[9];
  const float* b1b = (const float*)d_in[10];
  const float* Wc  = (const float*)d_in[11];
  const float* gc  = (const float*)d_in[12];
  const float* bc  = (const float*)d_in[13];
  float* out = (float*)d_out;

  const int M = in_sizes[1] / 27;          // 60000
  const int MT = (M + 63) / 64;            // 938
  const int MTO = (M + 127) / 128;         // 469
  // Mpad = MT*64 = MTO*128 = 60032

  char* ws = (char*)d_ws;
  unsigned short* h   = (unsigned short*)(ws + 0);           // [Mpad][256]
  unsigned short* wA  = (unsigned short*)(ws + 30736384);    // [Mpad][128]
  unsigned short* wP  = (unsigned short*)(ws + 46104576);    // [M][128]
  unsigned short* c3p = (unsigned short*)(ws + 61464576);    // [M][512]
  unsigned short* scp = (unsigned short*)(ws + 122904576);   // [M][512]
  unsigned short* w1a = (unsigned short*)(ws + 184344576);
  unsigned short* w3t = (unsigned short*)(ws + 184410112);
  unsigned short* w1b = (unsigned short*)(ws + 185294848);
  unsigned short* wc  = (unsigned short*)(ws + 185425920);
  float* ss1  = (float*)(ws + 185688064);
  float* ss2  = (float*)(ws + 185692160);
  float* ss3  = (float*)(ws + 185696256);
  float* sssc = (float*)(ws + 185700352);

  // Partials in ws regions dead at their point of use:
  float* part1  = (float*)(ws + 61464576);             // c3p+0   (gemm1 stats)
  float* part12 = (float*)(ws + 61464576 + 1048576);   // c3p+1MB (octree stats)
  float* partsc = (float*)(ws + 61464576 + 2097152);   // c3p+2MB (sc stats)
  float* part3  = (float*)wP;                          // wP dead after bnrelu2

  prep_transpose<<<432 + MT * 4, 256, 0, stream>>>(
      x, h, W1a, W3, W1b, Wc, w1a, w3t, w1b, wc, M, MT);

  const int total = M * 128, total2 = (MT * 64) * 128;
  const int bnGrid = (total2 / 8 + 255) / 256;

  // c1 = relu(bn(h @ W1a^T))   (wA pad rows zeroed for octree gather)
  gemm128<<<MTO, 512, 0, stream>>>(h, w1a, wP, part1, M, 256, 128, 1);
  bn_finalize<<<128, 256, 0, stream>>>(part1, MTO, 128, M, g1a, b1a, ss1);
  bnrelu<<<bnGrid, 256, 0, stream>>>(wP, ss1, wA, total, total2, 127);

  // FUSED: c2_pre = octree_conv(c1)  ||  sc_pre = h @ Wc^T
  octree_sc<<<MTO + 4 * MTO, 512, 0, stream>>>(
      wA, neigh, w3t, wP, part12, h, wc, scp, partsc, M, MTO);
  bn_finalize_dual<<<640, 256, 0, stream>>>(part12, partsc, MTO, M,
                                            g3, b3, gc, bc, ss2, sssc);
  bnrelu<<<bnGrid, 256, 0, stream>>>(wP, ss2, wA, total, total2, 127);

  // c3_pre = c2 @ W1b^T (stats -> part3 in wP region, dead after bnrelu2)
  gemm128<<<4 * MTO, 512, 0, stream>>>(wA, w1b, c3p, part3, M, 128, 512, 4);
  bn_finalize<<<512, 256, 0, stream>>>(part3, MTO, 512, M, g1b, b1b, ss3);

  // out = relu(bn(c3_pre) + bn(sc_pre)), transposed to [512][M]
  final_out<<<dim3(MT, 4), 256, 0, stream>>>(c3p, scp, ss3, sssc, out, M);
}